// Round 1
// baseline (4666.045 us; speedup 1.0000x reference)
//
#include <hip/hip_runtime.h>

#define TPB 256

// ---------------------------------------------------------------------------
// Generic direct conv: NCHW, weights OIHW. Block = 256 thr = 16(x) x 16(y)
// spatial tile, each thread does 2 rows (oh, oh+16) x CPT out-channels.
// Weights for this block's CPT channels staged in LDS (broadcast reads).
// ---------------------------------------------------------------------------
template<int KH, int KW, int S, int P, int CI, int CPT, bool RELU_IN, bool RELU_OUT>
__global__ __launch_bounds__(256)
void conv_k(const float* __restrict__ in, const float* __restrict__ wt,
            const float* __restrict__ bias, const float* res,
            float* out, int H, int W, int OH, int OW, int CO)
{
    constexpr int KHKW = KH * KW;
    __shared__ float sw[CPT * CI * KHKW];
    const int tid = threadIdx.x;
    const int co0 = blockIdx.y * CPT;
    const int n   = blockIdx.z;

    for (int e = tid; e < CPT * CI * KHKW; e += TPB) {
        int j    = e % CPT;
        int rest = e / CPT;
        int t    = rest % KHKW;
        int ci   = rest / KHKW;
        sw[e] = wt[((co0 + j) * CI + ci) * KHKW + t];
    }
    __syncthreads();

    const int tiles_x = OW >> 4;
    const int tx = tid & 15, ty = tid >> 4;
    const int ow  = (blockIdx.x % tiles_x) * 16 + tx;
    const int oh0 = (blockIdx.x / tiles_x) * 32 + ty;
    const int oh1 = oh0 + 16;

    float acc0[CPT], acc1[CPT];
#pragma unroll
    for (int j = 0; j < CPT; ++j) {
        float b = bias ? bias[co0 + j] : 0.f;
        acc0[j] = b; acc1[j] = b;
    }

    for (int ci = 0; ci < CI; ++ci) {
        const float* ip = in + ((n * CI + ci) * H) * W;
#pragma unroll
        for (int kh = 0; kh < KH; ++kh) {
            int ih0 = oh0 * S - P + kh;
            int ih1 = oh1 * S - P + kh;
            bool r0 = (unsigned)ih0 < (unsigned)H;
            bool r1 = (unsigned)ih1 < (unsigned)H;
#pragma unroll
            for (int kw = 0; kw < KW; ++kw) {
                int iw = ow * S - P + kw;
                bool c = (unsigned)iw < (unsigned)W;
                float v0 = (r0 && c) ? ip[ih0 * W + iw] : 0.f;
                float v1 = (r1 && c) ? ip[ih1 * W + iw] : 0.f;
                if (RELU_IN) { v0 = fmaxf(v0, 0.f); v1 = fmaxf(v1, 0.f); }
                const float* wp = &sw[(ci * KHKW + kh * KW + kw) * CPT];
#pragma unroll
                for (int j = 0; j < CPT; ++j) {
                    float wv = wp[j];
                    acc0[j] += v0 * wv;
                    acc1[j] += v1 * wv;
                }
            }
        }
    }

#pragma unroll
    for (int j = 0; j < CPT; ++j) {
        int co = co0 + j;
        float a0 = acc0[j], a1 = acc1[j];
        if (res) {
            a0 += res[((n * CO + co) * OH + oh0) * OW + ow];
            a1 += res[((n * CO + co) * OH + oh1) * OW + ow];
        }
        if (RELU_OUT) { a0 = fmaxf(a0, 0.f); a1 = fmaxf(a1, 0.f); }
        out[((n * CO + co) * OH + oh0) * OW + ow] = a0;
        out[((n * CO + co) * OH + oh1) * OW + ow] = a1;
    }
}

// ---------------------------------------------------------------------------
// ConvTranspose2d #1: in (16,128,64,64) -> out (16,64,128,128), k4 s2 p1,
// bias + relu. Weight dtw1 layout (in=128, out=64, 4, 4).
// out[oh,ow] gets taps where oh = ih*2 - 1 + kh  (2 valid kh, 2 valid kw).
// ---------------------------------------------------------------------------
__global__ __launch_bounds__(256)
void convt1_k(const float* __restrict__ in, const float* __restrict__ wt,
              const float* __restrict__ bias, float* out)
{
    __shared__ float sw[128 * 16 * 8];   // [(ci*16 + kh*4+kw)*8 + j]  (64 KB)
    const int tid = threadIdx.x;
    const int co0 = blockIdx.y * 8;
    const int n   = blockIdx.z;

    for (int e = tid; e < 16384; e += TPB) {
        int j  = e & 7;
        int t  = (e >> 3) & 15;
        int ci = e >> 7;
        sw[e] = wt[(ci * 64 + co0 + j) * 16 + t];
    }
    __syncthreads();

    const int tx = tid & 15, ty = tid >> 4;
    const int ow  = (blockIdx.x & 7) * 16 + tx;      // 128/16 = 8 tiles in x
    const int oh0 = (blockIdx.x >> 3) * 32 + ty;     // 4 tiles in y (2 rows/thr)

    const int p = (oh0 + 1) & 1;        // kh parity (same for oh0 and oh0+16)
    const int q = (ow + 1) & 1;         // kw parity
    const int ihA0 = (oh0 + 1 - p) >> 1;    // a=0: kh = p
    const int ihA1 = ihA0 - 1;              // a=1: kh = p+2
    const int iwB0 = (ow + 1 - q) >> 1;     // b=0: kw = q
    const int iwB1 = iwB0 - 1;              // b=1: kw = q+2
    const bool vw0 = (unsigned)iwB0 < 64u;
    const bool vw1 = (unsigned)iwB1 < 64u;

    float acc0[8], acc1[8];
#pragma unroll
    for (int j = 0; j < 8; ++j) { float b = bias[co0 + j]; acc0[j] = b; acc1[j] = b; }

    for (int ci = 0; ci < 128; ++ci) {
        const float* ip = in + ((n * 128 + ci) * 64) * 64;
#pragma unroll
        for (int a = 0; a < 2; ++a) {
            int kh  = p + 2 * a;
            int ihl = a ? ihA1 : ihA0;
            int ihh = ihl + 8;                      // for oh0+16
            bool vl = (unsigned)ihl < 64u;
            bool vh = (unsigned)ihh < 64u;
#pragma unroll
            for (int b = 0; b < 2; ++b) {
                int kw = q + 2 * b;
                int iw = b ? iwB1 : iwB0;
                bool vw = b ? vw1 : vw0;
                float v0 = (vl && vw) ? ip[ihl * 64 + iw] : 0.f;
                float v1 = (vh && vw) ? ip[ihh * 64 + iw] : 0.f;
                const float* wp = &sw[(ci * 16 + kh * 4 + kw) * 8];
#pragma unroll
                for (int j = 0; j < 8; ++j) {
                    float wv = wp[j];
                    acc0[j] += v0 * wv;
                    acc1[j] += v1 * wv;
                }
            }
        }
    }

    const int oh1 = oh0 + 16;
#pragma unroll
    for (int j = 0; j < 8; ++j) {
        int co = co0 + j;
        out[((n * 64 + co) * 128 + oh0) * 128 + ow] = fmaxf(acc0[j], 0.f);
        out[((n * 64 + co) * 128 + oh1) * 128 + ow] = fmaxf(acc1[j], 0.f);
    }
}

// ---------------------------------------------------------------------------
// ConvTranspose2d #2: in (16,64,128,128) -> out (16,1,256,256), k4 s2 p1,
// bias, no relu. Weight dtw2 layout (64, 1, 4, 4).
// ---------------------------------------------------------------------------
__global__ __launch_bounds__(256)
void convt2_k(const float* __restrict__ in, const float* __restrict__ wt,
              const float* __restrict__ bias, float* out)
{
    __shared__ float sw[1024];           // [ci*16 + kh*4 + kw]
    const int tid = threadIdx.x;
    for (int e = tid; e < 1024; e += TPB) sw[e] = wt[e];
    __syncthreads();

    const int tx = tid & 15, ty = tid >> 4;
    const int ow = (blockIdx.x & 15) * 16 + tx;      // 256/16 = 16 tiles x
    const int oh = (blockIdx.x >> 4) * 16 + ty;      // 16 tiles y
    const int n  = blockIdx.z;

    const int p = (oh + 1) & 1;
    const int q = (ow + 1) & 1;
    const int ih0 = (oh + 1 - p) >> 1, ih1 = ih0 - 1;
    const int iw0 = (ow + 1 - q) >> 1, iw1 = iw0 - 1;

    float acc = bias[0];
    for (int ci = 0; ci < 64; ++ci) {
        const float* ip = in + ((n * 64 + ci) * 128) * 128;
#pragma unroll
        for (int a = 0; a < 2; ++a) {
            int kh = p + 2 * a;
            int ih = a ? ih1 : ih0;
            bool vr = (unsigned)ih < 128u;
#pragma unroll
            for (int b = 0; b < 2; ++b) {
                int kw = q + 2 * b;
                int iw = b ? iw1 : iw0;
                float v = (vr && (unsigned)iw < 128u) ? ip[ih * 128 + iw] : 0.f;
                acc += v * sw[ci * 16 + kh * 4 + kw];
            }
        }
    }
    out[n * 65536 + oh * 256 + ow] = acc;
}

// ---------------------------------------------------------------------------
// VQ: per row r (65536 rows of 64), argmin_k |z - cb_k|^2, write quantized
// (NCHW), idx, counts, and squared-error sum. Codebook chunked through LDS.
// ---------------------------------------------------------------------------
__global__ __launch_bounds__(256)
void vq_k(const float* __restrict__ z, const float* __restrict__ cb,
          float* quant, int* idxp, int* counts, float* loss_sum)
{
    __shared__ float cbs[128 * 64];      // 32 KB chunk
    __shared__ float sqs[128];
    const int tid = threadIdx.x;
    const int r = blockIdx.x * 256 + tid;
    const int n = r >> 12;
    const int s = r & 4095;

    float zv[64];
#pragma unroll
    for (int d = 0; d < 64; ++d) zv[d] = z[((n << 6) + d) * 4096 + s];

    float best = 3.4e38f;
    int bi = 0;

    for (int ch = 0; ch < 4; ++ch) {
        __syncthreads();
        for (int e = tid; e < 8192; e += TPB) cbs[e] = cb[ch * 8192 + e];
        __syncthreads();
        if (tid < 128) {
            float sq = 0.f;
#pragma unroll
            for (int d = 0; d < 64; ++d) { float c = cbs[tid * 64 + d]; sq += c * c; }
            sqs[tid] = sq;
        }
        __syncthreads();
        for (int k = 0; k < 128; ++k) {
            const float4* cp = (const float4*)&cbs[k * 64];
            float dot = 0.f;
#pragma unroll
            for (int m = 0; m < 16; ++m) {
                float4 c = cp[m];
                dot += zv[4 * m] * c.x + zv[4 * m + 1] * c.y
                     + zv[4 * m + 2] * c.z + zv[4 * m + 3] * c.w;
            }
            float dist = sqs[k] - 2.f * dot;     // |z|^2 term is row-constant
            if (dist < best) { best = dist; bi = ch * 128 + k; }
        }
    }

    // quantized output + squared error (reload winning row from global; L2-hot)
    float err = 0.f;
    const float* crow = cb + bi * 64;
#pragma unroll
    for (int d = 0; d < 64; ++d) {
        float c = crow[d];
        float dd = zv[d] - c;
        err += dd * dd;
        quant[((n << 6) + d) * 4096 + s] = c;
    }
    idxp[r] = bi;
    atomicAdd(&counts[bi], 1);
#pragma unroll
    for (int o = 32; o; o >>= 1) err += __shfl_down(err, o, 64);
    if ((tid & 63) == 0) atomicAdd(loss_sum, err);
}

// loss + perplexity finalize (1 block, 512 threads)
__global__ __launch_bounds__(512)
void fin_k(const int* __restrict__ counts, const float* __restrict__ loss_sum,
           float* out_loss, float* out_perp)
{
    __shared__ float red[512];
    const int t = threadIdx.x;
    float avg = (float)counts[t] * (1.0f / 65536.0f);
    red[t] = avg * logf(avg + 1e-10f);
    __syncthreads();
    for (int st = 256; st > 0; st >>= 1) {
        if (t < st) red[t] += red[t + st];
        __syncthreads();
    }
    if (t == 0) {
        *out_perp = expf(-red[0]);
        *out_loss = loss_sum[0] * (1.25f / 4194304.0f);   // (1+0.25)*mean
    }
}

// one-hot encodings, written in a single pass (no memset needed)
__global__ __launch_bounds__(256)
void enc_k(const int* __restrict__ idxp, float* enc)
{
    int i = blockIdx.x * 256 + threadIdx.x;   // < 33554432
    int r = i >> 9;
    int k = i & 511;
    enc[i] = (idxp[r] == k) ? 1.0f : 0.0f;
}

// ---------------------------------------------------------------------------
extern "C" void kernel_launch(void* const* d_in, const int* in_sizes, int n_in,
                              void* d_out, int out_size, void* d_ws, size_t ws_size,
                              hipStream_t stream)
{
    const float* x    = (const float*)d_in[0];
    const float* ew1  = (const float*)d_in[1];
    const float* eb1  = (const float*)d_in[2];
    const float* ew2  = (const float*)d_in[3];
    const float* eb2  = (const float*)d_in[4];
    const float* ew3  = (const float*)d_in[5];
    const float* eb3  = (const float*)d_in[6];
    const float* er1a = (const float*)d_in[7];
    const float* er1b = (const float*)d_in[8];
    const float* er2a = (const float*)d_in[9];
    const float* er2b = (const float*)d_in[10];
    const float* pw   = (const float*)d_in[11];
    const float* pb   = (const float*)d_in[12];
    const float* cb   = (const float*)d_in[13];
    const float* dw1w = (const float*)d_in[14];
    const float* db1  = (const float*)d_in[15];
    const float* dr1a = (const float*)d_in[16];
    const float* dr1b = (const float*)d_in[17];
    const float* dr2a = (const float*)d_in[18];
    const float* dr2b = (const float*)d_in[19];
    const float* dtw1 = (const float*)d_in[20];
    const float* dtb1 = (const float*)d_in[21];
    const float* dtw2 = (const float*)d_in[22];
    const float* dtb2 = (const float*)d_in[23];

    // workspace layout (floats)
    float* ws   = (float*)d_ws;
    float* h2   = ws;                     // 16*128*64*64  = 8388608
    float* buf2 = ws + 8388608;           // 8388608 (h3 / res out / d1)
    float* mid  = ws + 16777216;          // 16*32*64*64   = 2097152
    float* z    = ws + 18874368;          // 16*64*64*64   = 4194304
    int*   idx  = (int*)(ws + 23068672);  // 65536
    int*   counts   = (int*)(ws + 23134208);   // 512
    float* loss_sum = ws + 23134720;           // 1
    if (ws_size < (size_t)23134728 * 4) return;   // not enough scratch

    // output layout
    float* out    = (float*)d_out;
    float* o_loss = out;                      // [0]
    float* xrec   = out + 1;                  // 16*1*256*256 = 1048576
    float* o_perp = out + 1048577;
    float* enc    = out + 1048578;            // 65536*512 = 33554432
    float* quant  = out + 34603010;           // 16*64*64*64 = 4194304
    // encodings region doubles as scratch until enc_k runs (written last):
    float* h1  = enc;                         // 16*64*128*128 = 16777216
    float* dt1 = enc + 16777216;              // 16*64*128*128 = 16777216

    hipMemsetAsync(counts, 0, 513 * 4, stream);   // counts + loss_sum

    // ---- encoder ----
    conv_k<4,4,2,1,  1,8,false,true ><<<dim3(32,  8, 16), TPB, 0, stream>>>(x,    ew1, eb1, nullptr, h1,  256,256,128,128,  64);
    conv_k<4,4,2,1, 64,8,false,true ><<<dim3( 8, 16, 16), TPB, 0, stream>>>(h1,   ew2, eb2, nullptr, h2,  128,128, 64, 64, 128);
    conv_k<3,3,1,1,128,8,false,false><<<dim3( 8, 16, 16), TPB, 0, stream>>>(h2,   ew3, eb3, nullptr, buf2, 64, 64, 64, 64, 128);
    conv_k<3,3,1,1,128,8,true ,true ><<<dim3( 8,  4, 16), TPB, 0, stream>>>(buf2, er1a, nullptr, nullptr, mid, 64,64,64,64, 32);
    conv_k<1,1,1,0, 32,8,false,false><<<dim3( 8, 16, 16), TPB, 0, stream>>>(mid,  er1b, nullptr, buf2, buf2, 64,64,64,64, 128);
    conv_k<3,3,1,1,128,8,true ,true ><<<dim3( 8,  4, 16), TPB, 0, stream>>>(buf2, er2a, nullptr, nullptr, mid, 64,64,64,64, 32);
    conv_k<1,1,1,0, 32,8,false,false><<<dim3( 8, 16, 16), TPB, 0, stream>>>(mid,  er2b, nullptr, buf2, buf2, 64,64,64,64, 128);
    conv_k<1,1,1,0,128,8,true ,false><<<dim3( 8,  8, 16), TPB, 0, stream>>>(buf2, pw,  pb,  nullptr, z,   64,64,64,64,  64);

    // ---- VQ ----
    vq_k<<<dim3(256), TPB, 0, stream>>>(z, cb, quant, idx, counts, loss_sum);
    fin_k<<<dim3(1), 512, 0, stream>>>(counts, loss_sum, o_loss, o_perp);

    // ---- decoder ----
    conv_k<3,3,1,1, 64,8,false,false><<<dim3( 8, 16, 16), TPB, 0, stream>>>(quant, dw1w, db1, nullptr, buf2, 64,64,64,64, 128);
    conv_k<3,3,1,1,128,8,true ,true ><<<dim3( 8,  4, 16), TPB, 0, stream>>>(buf2, dr1a, nullptr, nullptr, mid, 64,64,64,64, 32);
    conv_k<1,1,1,0, 32,8,false,false><<<dim3( 8, 16, 16), TPB, 0, stream>>>(mid,  dr1b, nullptr, buf2, buf2, 64,64,64,64, 128);
    conv_k<3,3,1,1,128,8,true ,true ><<<dim3( 8,  4, 16), TPB, 0, stream>>>(buf2, dr2a, nullptr, nullptr, mid, 64,64,64,64, 32);
    conv_k<1,1,1,0, 32,8,false,false><<<dim3( 8, 16, 16), TPB, 0, stream>>>(mid,  dr2b, nullptr, buf2, buf2, 64,64,64,64, 128);
    convt1_k<<<dim3(32, 8, 16), TPB, 0, stream>>>(buf2, dtw1, dtb1, dt1);
    convt2_k<<<dim3(256, 1, 16), TPB, 0, stream>>>(dt1, dtw2, dtb2, xrec);

    // ---- encodings (last: frees its region from scratch duty) ----
    enc_k<<<dim3(131072), TPB, 0, stream>>>(idx, enc);
}

// Round 2
// 1589.403 us; speedup vs baseline: 2.9357x; 2.9357x over previous
//
#include <hip/hip_runtime.h>

#define TPB 256

typedef __attribute__((ext_vector_type(8))) short s8v;
typedef __attribute__((ext_vector_type(4))) float f4v;
typedef __bf16 bf16x8v __attribute__((ext_vector_type(8)));

__device__ inline short f2b(float f) {
    unsigned u = __builtin_bit_cast(unsigned, f);
    unsigned r = (u + 0x7FFF + ((u >> 16) & 1)) >> 16;
    return (short)r;
}
__device__ inline float b2f(short s) {
    unsigned u = ((unsigned)(unsigned short)s) << 16;
    return __builtin_bit_cast(float, u);
}
__device__ inline f4v mfma16(s8v a, s8v b, f4v c) {
    return __builtin_amdgcn_mfma_f32_16x16x32_bf16(
        __builtin_bit_cast(bf16x8v, a), __builtin_bit_cast(bf16x8v, b), c, 0, 0, 0);
}

// ---------------------------------------------------------------------------
// Fused weight transpose: OIHW (or IOHW) fp32 -> [tap][co][ci] bf16
// ---------------------------------------------------------------------------
struct WtDesc { const float* src; int CO, CI, T, iohw, start; };
struct WtArgs { WtDesc d[13]; int total; };

__global__ __launch_bounds__(256)
void wtall_k(WtArgs a, short* dst)
{
    int i = blockIdx.x * 256 + threadIdx.x;
    if (i >= a.total) return;
    int s = 0;
    for (int j = 1; j < 13; ++j) if (i >= a.d[j].start) s = j;
    int off = i - a.d[s].start;
    int CI = a.d[s].CI, CO = a.d[s].CO, T = a.d[s].T;
    int ci = off % CI; int rest = off / CI; int co = rest % CO; int tap = rest / CO;
    float v = a.d[s].iohw ? a.d[s].src[(ci * CO + co) * T + tap]
                          : a.d[s].src[(co * CI + ci) * T + tap];
    dst[i] = f2b(v);
}

// ---------------------------------------------------------------------------
// conv1: fp32 direct, x (16,1,256,256) -> h1 NHWC bf16 (16,128,128,64)
// k4 s2 p1, bias, relu.
// ---------------------------------------------------------------------------
__global__ __launch_bounds__(256)
void conv1_k(const float* __restrict__ x, const float* __restrict__ w,
             const float* __restrict__ bias, short* __restrict__ out)
{
    __shared__ float sw[16 * 64];
    __shared__ float sb[64];
    const int tid = threadIdx.x;
    for (int e = tid; e < 1024; e += 256) { int co = e >> 4, tap = e & 15; sw[tap * 64 + co] = w[e]; }
    if (tid < 64) sb[tid] = bias[tid];
    __syncthreads();

    const int ow = tid & 127, ohl = tid >> 7;
    const int oh = blockIdx.x * 2 + ohl, n = blockIdx.y;
    const float* xp = x + (size_t)n * 65536;

    float acc[64];
#pragma unroll
    for (int c = 0; c < 64; ++c) acc[c] = sb[c];

#pragma unroll
    for (int kh = 0; kh < 4; ++kh) {
        int ih = oh * 2 - 1 + kh;
        bool vr = (unsigned)ih < 256u;
#pragma unroll
        for (int kw = 0; kw < 4; ++kw) {
            int iw = ow * 2 - 1 + kw;
            float v = (vr && (unsigned)iw < 256u) ? xp[ih * 256 + iw] : 0.f;
            const float* wp = &sw[(kh * 4 + kw) * 64];
#pragma unroll
            for (int c = 0; c < 64; ++c) acc[c] += v * wp[c];
        }
    }
    short* op = out + (((size_t)n * 128 + oh) * 128 + ow) * 64;
#pragma unroll
    for (int c = 0; c < 64; c += 8) {
        s8v sv;
#pragma unroll
        for (int j = 0; j < 8; ++j) sv[j] = f2b(fmaxf(acc[c + j], 0.f));
        *(s8v*)(op + c) = sv;
    }
}

// ---------------------------------------------------------------------------
// MFMA implicit-GEMM conv. in NHWC bf16 (64S x 64S x CI), out NHWC 64x64xCO.
// Block: M=128 (2 output rows) x N=CO. 4 waves, each 2 16-row sub-strips.
// ---------------------------------------------------------------------------
template<int KH, int KW, int S, int P, int CI, int CO,
         bool RELU_IN, bool RELU_OUT, bool RES, bool OUT_F32>
__global__ __launch_bounds__(256)
void mconv_k(const short* __restrict__ in, const short* __restrict__ wt,
             const float* __restrict__ bias, const short* __restrict__ res,
             void* __restrict__ outv)
{
    constexpr int NT = CO / 16;
    constexpr int KC = CI / 32;
    constexpr int T  = KH * KW;
    constexpr int H  = 64 * S, W = 64 * S;
    __shared__ short sA[128 * 40];
    __shared__ short sB[CO * 40];

    const int tid = threadIdx.x;
    const int oh0 = blockIdx.x * 2;
    const int n   = blockIdx.y;
    const short* inb = in + (size_t)n * H * W * CI;
    const int w = tid >> 6, l = tid & 63, rl = l & 15, qd = l >> 4;

    f4v acc0[NT], acc1[NT];
#pragma unroll
    for (int nt = 0; nt < NT; ++nt) { acc0[nt] = (f4v)0.f; acc1[nt] = (f4v)0.f; }

    for (int tap = 0; tap < T; ++tap) {
        const int kh = tap / KW, kw = tap % KW;
        const short* wp = wt + (size_t)tap * CO * CI;
        for (int kc = 0; kc < KC; ++kc) {
            __syncthreads();
            // stage A: 128 rows x 32 ci (bf16), padded stride 40 shorts
#pragma unroll
            for (int e = tid; e < 512; e += 256) {
                int row = e >> 2, kcn = e & 3;
                int ohl = row >> 6, ow = row & 63;
                int ih = (oh0 + ohl) * S - P + kh;
                int iw = ow * S - P + kw;
                s8v v = (s8v)0;
                if ((unsigned)ih < (unsigned)H && (unsigned)iw < (unsigned)W) {
                    v = *(const s8v*)(inb + ((size_t)ih * W + iw) * CI + kc * 32 + kcn * 8);
                    if (RELU_IN) {
#pragma unroll
                        for (int j = 0; j < 8; ++j) if (v[j] < (short)0) v[j] = 0;
                    }
                }
                *(s8v*)&sA[row * 40 + kcn * 8] = v;
            }
            // stage B: CO rows x 32 ci
            for (int e = tid; e < CO * 4; e += 256) {
                int co = e >> 2, kcn = e & 3;
                *(s8v*)&sB[co * 40 + kcn * 8] =
                    *(const s8v*)(wp + (size_t)co * CI + kc * 32 + kcn * 8);
            }
            __syncthreads();
            s8v a0 = *(const s8v*)&sA[(w * 32 + rl) * 40 + qd * 8];
            s8v a1 = *(const s8v*)&sA[(w * 32 + 16 + rl) * 40 + qd * 8];
#pragma unroll
            for (int nt = 0; nt < NT; ++nt) {
                s8v b = *(const s8v*)&sB[(nt * 16 + rl) * 40 + qd * 8];
                acc0[nt] = mfma16(a0, b, acc0[nt]);
                acc1[nt] = mfma16(a1, b, acc1[nt]);
            }
        }
    }

    // epilogue
#pragma unroll
    for (int sub = 0; sub < 2; ++sub) {
#pragma unroll
        for (int rg = 0; rg < 4; ++rg) {
            int m = w * 32 + sub * 16 + qd * 4 + rg;
            int ohl = m >> 6, ow = m & 63;
            size_t pb = ((size_t)n * 4096 + (size_t)(oh0 + ohl) * 64 + ow) * CO;
#pragma unroll
            for (int nt = 0; nt < NT; ++nt) {
                int co = nt * 16 + rl;
                float v = sub ? acc1[nt][rg] : acc0[nt][rg];
                if (bias) v += bias[co];
                if (RES) v += b2f(res[pb + co]);
                if (RELU_OUT) v = fmaxf(v, 0.f);
                if (OUT_F32) ((float*)outv)[pb + co] = v;
                else         ((short*)outv)[pb + co] = f2b(v);
            }
        }
    }
}

// ---------------------------------------------------------------------------
// ConvT1 as parity conv (MFMA): in NHWC bf16 (64,64,128) -> out (128,128,64),
// k4 s2 p1, bias+relu. Block: one ow-parity, 2 same-parity oh rows, M=128.
// ---------------------------------------------------------------------------
__global__ __launch_bounds__(256)
void mct1_k(const short* __restrict__ in, const short* __restrict__ wt,
            const float* __restrict__ bias, short* __restrict__ out)
{
    __shared__ short sA[128 * 40];
    __shared__ short sB[64 * 40];
    const int tid = threadIdx.x;
    const int bx = blockIdx.x;            // 0..127
    const int n  = blockIdx.y;
    const int P  = bx & 1;
    const int q2 = bx >> 1;
    const int oh0 = (q2 >> 1) * 4 + (q2 & 1);   // rows oh0, oh0+2 (same parity)
    const int p  = (oh0 + 1) & 1;
    const int ihb0 = (oh0 + 1 - p) >> 1;
    const short* inb = in + (size_t)n * 4096 * 128;
    const int w = tid >> 6, l = tid & 63, rl = l & 15, qd = l >> 4;

    f4v acc0[4], acc1[4];
#pragma unroll
    for (int nt = 0; nt < 4; ++nt) { acc0[nt] = (f4v)0.f; acc1[nt] = (f4v)0.f; }

    for (int a = 0; a < 2; ++a)
    for (int b = 0; b < 2; ++b) {
        const int kh = p + 2 * a;
        const int kw = (1 - P) + 2 * b;
        const short* wp = wt + (size_t)(kh * 4 + kw) * 64 * 128;
        for (int kc = 0; kc < 4; ++kc) {
            __syncthreads();
#pragma unroll
            for (int e = tid; e < 512; e += 256) {
                int row = e >> 2, kcn = e & 3;
                int ohl = row >> 6, j = row & 63;
                int ih = ihb0 + ohl - a;
                int iw = j + P - b;
                s8v v = (s8v)0;
                if ((unsigned)ih < 64u && (unsigned)iw < 64u)
                    v = *(const s8v*)(inb + ((size_t)(ih * 64 + iw)) * 128 + kc * 32 + kcn * 8);
                *(s8v*)&sA[row * 40 + kcn * 8] = v;
            }
            if (tid < 256) {
                int e = tid;
                if (e < 256) {
                    int co = e >> 2, kcn = e & 3;
                    *(s8v*)&sB[co * 40 + kcn * 8] =
                        *(const s8v*)(wp + (size_t)co * 128 + kc * 32 + kcn * 8);
                }
            }
            __syncthreads();
            s8v a0 = *(const s8v*)&sA[(w * 32 + rl) * 40 + qd * 8];
            s8v a1 = *(const s8v*)&sA[(w * 32 + 16 + rl) * 40 + qd * 8];
#pragma unroll
            for (int nt = 0; nt < 4; ++nt) {
                s8v bb = *(const s8v*)&sB[(nt * 16 + rl) * 40 + qd * 8];
                acc0[nt] = mfma16(a0, bb, acc0[nt]);
                acc1[nt] = mfma16(a1, bb, acc1[nt]);
            }
        }
    }

#pragma unroll
    for (int sub = 0; sub < 2; ++sub) {
#pragma unroll
        for (int rg = 0; rg < 4; ++rg) {
            int m = w * 32 + sub * 16 + qd * 4 + rg;
            int ohl = m >> 6, j = m & 63;
            int oh = oh0 + 2 * ohl, ow = 2 * j + P;
            size_t pb = (((size_t)n * 128 + oh) * 128 + ow) * 64;
#pragma unroll
            for (int nt = 0; nt < 4; ++nt) {
                int co = nt * 16 + rl;
                float v = (sub ? acc1[nt][rg] : acc0[nt][rg]) + bias[co];
                out[pb + co] = f2b(fmaxf(v, 0.f));
            }
        }
    }
}

// ---------------------------------------------------------------------------
// ConvT2: in NHWC bf16 (16,128,128,64) -> x_rec fp32 (16,256,256), k4 s2 p1.
// ---------------------------------------------------------------------------
__global__ __launch_bounds__(256)
void convt2_k(const short* __restrict__ in, const float* __restrict__ w,
              const float* __restrict__ bias, float* __restrict__ out)
{
    __shared__ float sw[16 * 64];   // [tap][ci]
    const int tid = threadIdx.x;
    for (int e = tid; e < 1024; e += 256) { int ci = e >> 4, tap = e & 15; sw[tap * 64 + ci] = w[e]; }
    __syncthreads();

    const int i = blockIdx.x * 256 + tid;
    const int n = i >> 16, s = i & 65535;
    const int oh = s >> 8, ow = s & 255;

    const int p = (oh + 1) & 1, q = (ow + 1) & 1;
    const int ihb = (oh + 1 - p) >> 1, iwb = (ow + 1 - q) >> 1;

    float acc = bias[0];
#pragma unroll
    for (int a = 0; a < 2; ++a) {
        int ih = ihb - a, kh = p + 2 * a;
        bool vr = (unsigned)ih < 128u;
#pragma unroll
        for (int b = 0; b < 2; ++b) {
            int iw = iwb - b, kw = q + 2 * b;
            if (vr && (unsigned)iw < 128u) {
                const short* ip = in + (((size_t)n * 128 + ih) * 128 + iw) * 64;
                const float* wp = &sw[(kh * 4 + kw) * 64];
#pragma unroll
                for (int c = 0; c < 64; c += 8) {
                    s8v v = *(const s8v*)(ip + c);
#pragma unroll
                    for (int j = 0; j < 8; ++j) acc += b2f(v[j]) * wp[c + j];
                }
            }
        }
    }
    out[i] = acc;
}

// ---------------------------------------------------------------------------
// VQ: z fp32 NHWC rows [65536][64]; 2 rows/thread; exact fp32 argmin.
// ---------------------------------------------------------------------------
__global__ __launch_bounds__(256)
void vq_k(const float* __restrict__ z, const float* __restrict__ cb,
          float* __restrict__ quant, short* __restrict__ qb,
          int* __restrict__ idxp, int* __restrict__ counts, float* __restrict__ loss_sum)
{
    __shared__ float cbs[128 * 64];
    __shared__ float sqs[128];
    const int tid = threadIdx.x;
    const int r0 = (blockIdx.x * 256 + tid) * 2;

    float zv[2][64];
    const float4* zp = (const float4*)(z + (size_t)r0 * 64);
#pragma unroll
    for (int m = 0; m < 16; ++m) {
        float4 t = zp[m];
        zv[0][4 * m] = t.x; zv[0][4 * m + 1] = t.y; zv[0][4 * m + 2] = t.z; zv[0][4 * m + 3] = t.w;
    }
#pragma unroll
    for (int m = 0; m < 16; ++m) {
        float4 t = zp[16 + m];
        zv[1][4 * m] = t.x; zv[1][4 * m + 1] = t.y; zv[1][4 * m + 2] = t.z; zv[1][4 * m + 3] = t.w;
    }

    float best0 = 3.4e38f, best1 = 3.4e38f;
    int bi0 = 0, bi1 = 0;

    for (int ch = 0; ch < 4; ++ch) {
        __syncthreads();
        for (int e = tid; e < 8192; e += TPB) cbs[e] = cb[ch * 8192 + e];
        __syncthreads();
        if (tid < 128) {
            float sq = 0.f;
#pragma unroll
            for (int d = 0; d < 64; ++d) { float c = cbs[tid * 64 + d]; sq += c * c; }
            sqs[tid] = sq;
        }
        __syncthreads();
        for (int k = 0; k < 128; ++k) {
            const float4* cp = (const float4*)&cbs[k * 64];
            float d0 = 0.f, d1 = 0.f;
#pragma unroll
            for (int m = 0; m < 16; ++m) {
                float4 c = cp[m];
                d0 += zv[0][4 * m] * c.x + zv[0][4 * m + 1] * c.y
                    + zv[0][4 * m + 2] * c.z + zv[0][4 * m + 3] * c.w;
                d1 += zv[1][4 * m] * c.x + zv[1][4 * m + 1] * c.y
                    + zv[1][4 * m + 2] * c.z + zv[1][4 * m + 3] * c.w;
            }
            float dist0 = sqs[k] - 2.f * d0;
            float dist1 = sqs[k] - 2.f * d1;
            if (dist0 < best0) { best0 = dist0; bi0 = ch * 128 + k; }
            if (dist1 < best1) { best1 = dist1; bi1 = ch * 128 + k; }
        }
    }

    float err = 0.f;
#pragma unroll
    for (int rr = 0; rr < 2; ++rr) {
        int r = r0 + rr;
        int bi = rr ? bi1 : bi0;
        int n = r >> 12, s = r & 4095;
        const float* crow = cb + (size_t)bi * 64;
        short* qrow = qb + (size_t)r * 64;
#pragma unroll
        for (int d = 0; d < 64; ++d) {
            float c = crow[d];
            float dd = zv[rr][d] - c;
            err += dd * dd;
            quant[((size_t)((n << 6) + d)) * 4096 + s] = c;
            qrow[d] = f2b(c);
        }
        idxp[r] = bi;
        atomicAdd(&counts[bi], 1);
    }
#pragma unroll
    for (int o = 32; o; o >>= 1) err += __shfl_down(err, o, 64);
    if ((tid & 63) == 0) atomicAdd(loss_sum, err);
}

__global__ __launch_bounds__(512)
void fin_k(const int* __restrict__ counts, const float* __restrict__ loss_sum,
           float* out_loss, float* out_perp)
{
    __shared__ float red[512];
    const int t = threadIdx.x;
    float avg = (float)counts[t] * (1.0f / 65536.0f);
    red[t] = avg * logf(avg + 1e-10f);
    __syncthreads();
    for (int st = 256; st > 0; st >>= 1) {
        if (t < st) red[t] += red[t + st];
        __syncthreads();
    }
    if (t == 0) {
        *out_perp = expf(-red[0]);
        *out_loss = loss_sum[0] * (1.25f / 4194304.0f);
    }
}

__global__ __launch_bounds__(256)
void enc_k(const int* __restrict__ idxp, float2* __restrict__ enc)
{
    int i = blockIdx.x * 256 + threadIdx.x;    // < 16777216 float2s
    int r = i >> 8, c2 = i & 255;
    int k = idxp[r];
    float2 v; v.x = (k == c2 * 2) ? 1.f : 0.f; v.y = (k == c2 * 2 + 1) ? 1.f : 0.f;
    enc[i] = v;
}

// ---------------------------------------------------------------------------
extern "C" void kernel_launch(void* const* d_in, const int* in_sizes, int n_in,
                              void* d_out, int out_size, void* d_ws, size_t ws_size,
                              hipStream_t stream)
{
    const float* x    = (const float*)d_in[0];
    const float* ew1  = (const float*)d_in[1];
    const float* eb1  = (const float*)d_in[2];
    const float* ew2  = (const float*)d_in[3];
    const float* eb2  = (const float*)d_in[4];
    const float* ew3  = (const float*)d_in[5];
    const float* eb3  = (const float*)d_in[6];
    const float* er1a = (const float*)d_in[7];
    const float* er1b = (const float*)d_in[8];
    const float* er2a = (const float*)d_in[9];
    const float* er2b = (const float*)d_in[10];
    const float* pw   = (const float*)d_in[11];
    const float* pb   = (const float*)d_in[12];
    const float* cb   = (const float*)d_in[13];
    const float* dw1w = (const float*)d_in[14];
    const float* db1  = (const float*)d_in[15];
    const float* dr1a = (const float*)d_in[16];
    const float* dr1b = (const float*)d_in[17];
    const float* dr2a = (const float*)d_in[18];
    const float* dr2b = (const float*)d_in[19];
    const float* dtw1 = (const float*)d_in[20];
    const float* dtb1 = (const float*)d_in[21];
    const float* dtw2 = (const float*)d_in[22];
    const float* dtb2 = (const float*)d_in[23];

    // ---- workspace layout ----
    char* wsb = (char*)d_ws;
    short* wbase = (short*)wsb;
    short* wt2   = wbase;            // 16*128*64  = 131072
    short* wt3   = wbase + 131072;   // 9*128*128  = 147456
    short* wr1a  = wbase + 278528;   // 9*32*128   = 36864
    short* wr1b  = wbase + 315392;   // 128*32     = 4096
    short* wr2a  = wbase + 319488;
    short* wr2b  = wbase + 356352;
    short* wpwt  = wbase + 360448;   // 64*128     = 8192
    short* wd1   = wbase + 368640;   // 9*128*64   = 73728
    short* wdr1a = wbase + 442368;
    short* wdr1b = wbase + 479232;
    short* wdr2a = wbase + 483328;
    short* wdr2b = wbase + 520192;
    short* wtt1  = wbase + 524288;   // 16*64*128  = 131072  (end 655360)

    short* h2   = (short*)(wsb + 1310720);     // 8388608 bf16
    short* buf  = (short*)(wsb + 18087936);    // 8388608 bf16
    short* mid  = (short*)(wsb + 34865152);    // 2097152 bf16
    short* qb   = (short*)(wsb + 39059456);    // 4194304 bf16
    float* z    = (float*)(wsb + 47448064);    // 4194304 fp32
    int*   idx  = (int*)  (wsb + 64225280);    // 65536
    int*   counts   = (int*)(wsb + 64487424);  // 512
    float* loss_sum = (float*)(wsb + 64489472);
    if (ws_size < (size_t)64489480) return;

    // ---- output layout ----
    float* out    = (float*)d_out;
    float* o_loss = out;
    float* xrec   = out + 1;                   // 1048576
    float* o_perp = out + 1048577;
    float* enc    = out + 1048578;             // 33554432
    float* quant  = out + 34603010;            // 4194304
    // scratch inside enc region (dead until enc_k, which runs last):
    short* h1  = (short*)((char*)d_out + (size_t)1048580 * 4);  // 16-B aligned
    short* dt1 = h1 + 16777216;

    hipMemsetAsync(counts, 0, 516 * 4, stream);   // counts + loss_sum

    // ---- weight transpose (one fused launch) ----
    WtArgs wa;
    wa.d[0]  = { ew2,  128,  64, 16, 0, 0      };
    wa.d[1]  = { ew3,  128, 128,  9, 0, 131072 };
    wa.d[2]  = { er1a,  32, 128,  9, 0, 278528 };
    wa.d[3]  = { er1b, 128,  32,  1, 0, 315392 };
    wa.d[4]  = { er2a,  32, 128,  9, 0, 319488 };
    wa.d[5]  = { er2b, 128,  32,  1, 0, 356352 };
    wa.d[6]  = { pw,    64, 128,  1, 0, 360448 };
    wa.d[7]  = { dw1w, 128,  64,  9, 0, 368640 };
    wa.d[8]  = { dr1a,  32, 128,  9, 0, 442368 };
    wa.d[9]  = { dr1b, 128,  32,  1, 0, 479232 };
    wa.d[10] = { dr2a,  32, 128,  9, 0, 483328 };
    wa.d[11] = { dr2b, 128,  32,  1, 0, 520192 };
    wa.d[12] = { dtw1,  64, 128, 16, 1, 524288 };
    wa.total = 655360;
    wtall_k<<<dim3(2560), TPB, 0, stream>>>(wa, wbase);

    // ---- encoder ----
    conv1_k<<<dim3(64, 16), TPB, 0, stream>>>(x, ew1, eb1, h1);
    mconv_k<4,4,2,1, 64,128,false,true ,false,false><<<dim3(32,16), TPB, 0, stream>>>(h1,  wt2,  eb2, nullptr, h2);
    mconv_k<3,3,1,1,128,128,false,false,false,false><<<dim3(32,16), TPB, 0, stream>>>(h2,  wt3,  eb3, nullptr, buf);
    mconv_k<3,3,1,1,128, 32,true ,true ,false,false><<<dim3(32,16), TPB, 0, stream>>>(buf, wr1a, nullptr, nullptr, mid);
    mconv_k<1,1,1,0, 32,128,false,false,true ,false><<<dim3(32,16), TPB, 0, stream>>>(mid, wr1b, nullptr, buf, buf);
    mconv_k<3,3,1,1,128, 32,true ,true ,false,false><<<dim3(32,16), TPB, 0, stream>>>(buf, wr2a, nullptr, nullptr, mid);
    mconv_k<1,1,1,0, 32,128,false,false,true ,false><<<dim3(32,16), TPB, 0, stream>>>(mid, wr2b, nullptr, buf, buf);
    mconv_k<1,1,1,0,128, 64,true ,false,false,true ><<<dim3(32,16), TPB, 0, stream>>>(buf, wpwt, pb, nullptr, z);

    // ---- VQ ----
    vq_k<<<dim3(128), TPB, 0, stream>>>(z, cb, quant, qb, idx, counts, loss_sum);
    fin_k<<<dim3(1), 512, 0, stream>>>(counts, loss_sum, o_loss, o_perp);

    // ---- decoder ----
    mconv_k<3,3,1,1, 64,128,false,false,false,false><<<dim3(32,16), TPB, 0, stream>>>(qb,  wd1,   db1, nullptr, buf);
    mconv_k<3,3,1,1,128, 32,true ,true ,false,false><<<dim3(32,16), TPB, 0, stream>>>(buf, wdr1a, nullptr, nullptr, mid);
    mconv_k<1,1,1,0, 32,128,false,false,true ,false><<<dim3(32,16), TPB, 0, stream>>>(mid, wdr1b, nullptr, buf, buf);
    mconv_k<3,3,1,1,128, 32,true ,true ,false,false><<<dim3(32,16), TPB, 0, stream>>>(buf, wdr2a, nullptr, nullptr, mid);
    mconv_k<1,1,1,0, 32,128,false,false,true ,false><<<dim3(32,16), TPB, 0, stream>>>(mid, wdr2b, nullptr, buf, buf);
    mct1_k<<<dim3(128, 16), TPB, 0, stream>>>(buf, wtt1, dtb1, dt1);
    convt2_k<<<dim3(4096), TPB, 0, stream>>>(dt1, dtw2, dtb2, xrec);

    // ---- encodings (last) ----
    enc_k<<<dim3(65536), TPB, 0, stream>>>(idx, (float2*)enc);
}

// Round 3
// 1049.876 us; speedup vs baseline: 4.4444x; 1.5139x over previous
//
#include <hip/hip_runtime.h>

#define TPB 256

typedef __attribute__((ext_vector_type(8))) short s8v;
typedef __attribute__((ext_vector_type(4))) float f4v;
typedef __bf16 bf16x8v __attribute__((ext_vector_type(8)));

__device__ inline short f2b(float f) {
    unsigned u = __builtin_bit_cast(unsigned, f);
    unsigned r = (u + 0x7FFF + ((u >> 16) & 1)) >> 16;
    return (short)r;
}
__device__ inline float b2f(short s) {
    unsigned u = ((unsigned)(unsigned short)s) << 16;
    return __builtin_bit_cast(float, u);
}
__device__ inline f4v mfma16(s8v a, s8v b, f4v c) {
    return __builtin_amdgcn_mfma_f32_16x16x32_bf16(
        __builtin_bit_cast(bf16x8v, a), __builtin_bit_cast(bf16x8v, b), c, 0, 0, 0);
}

// ---------------------------------------------------------------------------
// Fused weight transpose: OIHW (or IOHW) fp32 -> [tap][co][ci] bf16
// ---------------------------------------------------------------------------
struct WtDesc { const float* src; int CO, CI, T, iohw, start; };
struct WtArgs { WtDesc d[13]; int total; };

__global__ __launch_bounds__(256)
void wtall_k(WtArgs a, short* dst)
{
    int i = blockIdx.x * 256 + threadIdx.x;
    if (i >= a.total) return;
    int s = 0;
    for (int j = 1; j < 13; ++j) if (i >= a.d[j].start) s = j;
    int off = i - a.d[s].start;
    int CI = a.d[s].CI, CO = a.d[s].CO, T = a.d[s].T;
    int ci = off % CI; int rest = off / CI; int co = rest % CO; int tap = rest / CO;
    float v = a.d[s].iohw ? a.d[s].src[(ci * CO + co) * T + tap]
                          : a.d[s].src[(co * CI + ci) * T + tap];
    dst[i] = f2b(v);
}

// ---------------------------------------------------------------------------
// conv1: x (16,1,256,256) fp32 -> h1 NHWC bf16 (16,128,128,64), k4 s2 p1,
// bias+relu. One block per (n, oh): 4 input rows staged in LDS; lane = co,
// 16 weights + 1 acc per thread (no spill); wave stores 128-B contiguous.
// ---------------------------------------------------------------------------
__global__ __launch_bounds__(256)
void conv1_k(const float* __restrict__ x, const float* __restrict__ w,
             const float* __restrict__ bias, short* __restrict__ out)
{
    __shared__ float sx[4 * 256];
    const int tid = threadIdx.x;
    const int oh = blockIdx.x, n = blockIdx.y;
    const int co = tid & 63, wv = tid >> 6;

    float wr[16];
#pragma unroll
    for (int t = 0; t < 16; ++t) wr[t] = w[co * 16 + t];
    const float b = bias[co];

    const float* xp = x + (size_t)n * 65536;
    for (int e = tid; e < 1024; e += 256) {
        int kh = e >> 8, col = e & 255;
        int ih = oh * 2 - 1 + kh;
        sx[e] = ((unsigned)ih < 256u) ? xp[ih * 256 + col] : 0.f;
    }
    __syncthreads();

    short* op = out + (((size_t)n * 128 + oh) * 128) * 64 + co;
#pragma unroll 4
    for (int i = 0; i < 32; ++i) {
        int ow = wv * 32 + i;
        int iwb = ow * 2 - 1;
        float acc = b;
#pragma unroll
        for (int kh = 0; kh < 4; ++kh) {
#pragma unroll
            for (int kw = 0; kw < 4; ++kw) {
                int iw = iwb + kw;
                float v = ((unsigned)iw < 256u) ? sx[kh * 256 + iw] : 0.f;
                acc = fmaf(v, wr[kh * 4 + kw], acc);
            }
        }
        op[(size_t)ow * 64] = f2b(fmaxf(acc, 0.f));
    }
}

// ---------------------------------------------------------------------------
// MFMA implicit-GEMM conv. in NHWC bf16 (64S x 64S x CI), out NHWC 64x64xCO.
// Block: M=128 (2 output rows) x N=CO. 4 waves, each 2 16-row sub-strips.
// ---------------------------------------------------------------------------
template<int KH, int KW, int S, int P, int CI, int CO,
         bool RELU_IN, bool RELU_OUT, bool RES, bool OUT_F32>
__global__ __launch_bounds__(256)
void mconv_k(const short* __restrict__ in, const short* __restrict__ wt,
             const float* __restrict__ bias, const short* __restrict__ res,
             void* __restrict__ outv)
{
    constexpr int NT = CO / 16;
    constexpr int KC = CI / 32;
    constexpr int T  = KH * KW;
    constexpr int H  = 64 * S, W = 64 * S;
    __shared__ short sA[128 * 40];
    __shared__ short sB[CO * 40];

    const int tid = threadIdx.x;
    const int oh0 = blockIdx.x * 2;
    const int n   = blockIdx.y;
    const short* inb = in + (size_t)n * H * W * CI;
    const int w = tid >> 6, l = tid & 63, rl = l & 15, qd = l >> 4;

    f4v acc0[NT], acc1[NT];
#pragma unroll
    for (int nt = 0; nt < NT; ++nt) { acc0[nt] = (f4v)0.f; acc1[nt] = (f4v)0.f; }

    for (int tap = 0; tap < T; ++tap) {
        const int kh = tap / KW, kw = tap % KW;
        const short* wp = wt + (size_t)tap * CO * CI;
        for (int kc = 0; kc < KC; ++kc) {
            __syncthreads();
#pragma unroll
            for (int e = tid; e < 512; e += 256) {
                int row = e >> 2, kcn = e & 3;
                int ohl = row >> 6, ow = row & 63;
                int ih = (oh0 + ohl) * S - P + kh;
                int iw = ow * S - P + kw;
                s8v v = (s8v)0;
                if ((unsigned)ih < (unsigned)H && (unsigned)iw < (unsigned)W) {
                    v = *(const s8v*)(inb + ((size_t)ih * W + iw) * CI + kc * 32 + kcn * 8);
                    if (RELU_IN) {
#pragma unroll
                        for (int j = 0; j < 8; ++j) if (v[j] < (short)0) v[j] = 0;
                    }
                }
                *(s8v*)&sA[row * 40 + kcn * 8] = v;
            }
            for (int e = tid; e < CO * 4; e += 256) {
                int co = e >> 2, kcn = e & 3;
                *(s8v*)&sB[co * 40 + kcn * 8] =
                    *(const s8v*)(wp + (size_t)co * CI + kc * 32 + kcn * 8);
            }
            __syncthreads();
            s8v a0 = *(const s8v*)&sA[(w * 32 + rl) * 40 + qd * 8];
            s8v a1 = *(const s8v*)&sA[(w * 32 + 16 + rl) * 40 + qd * 8];
#pragma unroll
            for (int nt = 0; nt < NT; ++nt) {
                s8v b = *(const s8v*)&sB[(nt * 16 + rl) * 40 + qd * 8];
                acc0[nt] = mfma16(a0, b, acc0[nt]);
                acc1[nt] = mfma16(a1, b, acc1[nt]);
            }
        }
    }

#pragma unroll
    for (int sub = 0; sub < 2; ++sub) {
#pragma unroll
        for (int rg = 0; rg < 4; ++rg) {
            int m = w * 32 + sub * 16 + qd * 4 + rg;
            int ohl = m >> 6, ow = m & 63;
            size_t pb = ((size_t)n * 4096 + (size_t)(oh0 + ohl) * 64 + ow) * CO;
#pragma unroll
            for (int nt = 0; nt < NT; ++nt) {
                int co = nt * 16 + rl;
                float v = sub ? acc1[nt][rg] : acc0[nt][rg];
                if (bias) v += bias[co];
                if (RES) v += b2f(res[pb + co]);
                if (RELU_OUT) v = fmaxf(v, 0.f);
                if (OUT_F32) ((float*)outv)[pb + co] = v;
                else         ((short*)outv)[pb + co] = f2b(v);
            }
        }
    }
}

// ---------------------------------------------------------------------------
// ConvT1 as parity conv (MFMA): in NHWC bf16 (64,64,128) -> out (128,128,64)
// ---------------------------------------------------------------------------
__global__ __launch_bounds__(256)
void mct1_k(const short* __restrict__ in, const short* __restrict__ wt,
            const float* __restrict__ bias, short* __restrict__ out)
{
    __shared__ short sA[128 * 40];
    __shared__ short sB[64 * 40];
    const int tid = threadIdx.x;
    const int bx = blockIdx.x;
    const int n  = blockIdx.y;
    const int P  = bx & 1;
    const int q2 = bx >> 1;
    const int oh0 = (q2 >> 1) * 4 + (q2 & 1);
    const int p  = (oh0 + 1) & 1;
    const int ihb0 = (oh0 + 1 - p) >> 1;
    const short* inb = in + (size_t)n * 4096 * 128;
    const int w = tid >> 6, l = tid & 63, rl = l & 15, qd = l >> 4;

    f4v acc0[4], acc1[4];
#pragma unroll
    for (int nt = 0; nt < 4; ++nt) { acc0[nt] = (f4v)0.f; acc1[nt] = (f4v)0.f; }

    for (int a = 0; a < 2; ++a)
    for (int b = 0; b < 2; ++b) {
        const int kh = p + 2 * a;
        const int kw = (1 - P) + 2 * b;
        const short* wp = wt + (size_t)(kh * 4 + kw) * 64 * 128;
        for (int kc = 0; kc < 4; ++kc) {
            __syncthreads();
#pragma unroll
            for (int e = tid; e < 512; e += 256) {
                int row = e >> 2, kcn = e & 3;
                int ohl = row >> 6, j = row & 63;
                int ih = ihb0 + ohl - a;
                int iw = j + P - b;
                s8v v = (s8v)0;
                if ((unsigned)ih < 64u && (unsigned)iw < 64u)
                    v = *(const s8v*)(inb + ((size_t)(ih * 64 + iw)) * 128 + kc * 32 + kcn * 8);
                *(s8v*)&sA[row * 40 + kcn * 8] = v;
            }
            {
                int e = tid;
                if (e < 256) {
                    int co = e >> 2, kcn = e & 3;
                    *(s8v*)&sB[co * 40 + kcn * 8] =
                        *(const s8v*)(wp + (size_t)co * 128 + kc * 32 + kcn * 8);
                }
            }
            __syncthreads();
            s8v a0 = *(const s8v*)&sA[(w * 32 + rl) * 40 + qd * 8];
            s8v a1 = *(const s8v*)&sA[(w * 32 + 16 + rl) * 40 + qd * 8];
#pragma unroll
            for (int nt = 0; nt < 4; ++nt) {
                s8v bb = *(const s8v*)&sB[(nt * 16 + rl) * 40 + qd * 8];
                acc0[nt] = mfma16(a0, bb, acc0[nt]);
                acc1[nt] = mfma16(a1, bb, acc1[nt]);
            }
        }
    }

#pragma unroll
    for (int sub = 0; sub < 2; ++sub) {
#pragma unroll
        for (int rg = 0; rg < 4; ++rg) {
            int m = w * 32 + sub * 16 + qd * 4 + rg;
            int ohl = m >> 6, j = m & 63;
            int oh = oh0 + 2 * ohl, ow = 2 * j + P;
            size_t pb = (((size_t)n * 128 + oh) * 128 + ow) * 64;
#pragma unroll
            for (int nt = 0; nt < 4; ++nt) {
                int co = nt * 16 + rl;
                float v = (sub ? acc1[nt][rg] : acc0[nt][rg]) + bias[co];
                out[pb + co] = f2b(fmaxf(v, 0.f));
            }
        }
    }
}

// ---------------------------------------------------------------------------
// ConvT2: in NHWC bf16 (16,128,128,64) -> x_rec fp32 (16,256,256), k4 s2 p1.
// ---------------------------------------------------------------------------
__global__ __launch_bounds__(256)
void convt2_k(const short* __restrict__ in, const float* __restrict__ w,
              const float* __restrict__ bias, float* __restrict__ out)
{
    __shared__ float sw[16 * 64];
    const int tid = threadIdx.x;
    for (int e = tid; e < 1024; e += 256) { int ci = e >> 4, tap = e & 15; sw[tap * 64 + ci] = w[e]; }
    __syncthreads();

    const int i = blockIdx.x * 256 + tid;
    const int n = i >> 16, s = i & 65535;
    const int oh = s >> 8, ow = s & 255;

    const int p = (oh + 1) & 1, q = (ow + 1) & 1;
    const int ihb = (oh + 1 - p) >> 1, iwb = (ow + 1 - q) >> 1;

    float acc = bias[0];
#pragma unroll
    for (int a = 0; a < 2; ++a) {
        int ih = ihb - a, kh = p + 2 * a;
        bool vr = (unsigned)ih < 128u;
#pragma unroll
        for (int b = 0; b < 2; ++b) {
            int iw = iwb - b, kw = q + 2 * b;
            if (vr && (unsigned)iw < 128u) {
                const short* ip = in + (((size_t)n * 128 + ih) * 128 + iw) * 64;
                const float* wp = &sw[(kh * 4 + kw) * 64];
#pragma unroll
                for (int c = 0; c < 64; c += 8) {
                    s8v v = *(const s8v*)(ip + c);
#pragma unroll
                    for (int j = 0; j < 8; ++j) acc += b2f(v[j]) * wp[c + j];
                }
            }
        }
    }
    out[i] = acc;
}

// ---------------------------------------------------------------------------
// VQ: z fp32 NHWC rows [65536][64]; rows (r, r+256) per thread so NCHW
// quant stores are lane-contiguous; exact fp32 argmin.
// ---------------------------------------------------------------------------
__global__ __launch_bounds__(256)
void vq_k(const float* __restrict__ z, const float* __restrict__ cb,
          float* __restrict__ quant, short* __restrict__ qb,
          int* __restrict__ idxp, int* __restrict__ counts, float* __restrict__ loss_sum)
{
    __shared__ float cbs[128 * 64];
    __shared__ float sqs[128];
    const int tid = threadIdx.x;
    const int rA = blockIdx.x * 512 + tid;
    const int rB = rA + 256;

    float zv[2][64];
#pragma unroll
    for (int rr = 0; rr < 2; ++rr) {
        const float4* zp = (const float4*)(z + (size_t)(rr ? rB : rA) * 64);
#pragma unroll
        for (int m = 0; m < 16; ++m) {
            float4 t = zp[m];
            zv[rr][4 * m] = t.x; zv[rr][4 * m + 1] = t.y;
            zv[rr][4 * m + 2] = t.z; zv[rr][4 * m + 3] = t.w;
        }
    }

    float best0 = 3.4e38f, best1 = 3.4e38f;
    int bi0 = 0, bi1 = 0;

    for (int ch = 0; ch < 4; ++ch) {
        __syncthreads();
        for (int e = tid; e < 8192; e += TPB) cbs[e] = cb[ch * 8192 + e];
        __syncthreads();
        if (tid < 128) {
            float sq = 0.f;
#pragma unroll
            for (int d = 0; d < 64; ++d) { float c = cbs[tid * 64 + d]; sq += c * c; }
            sqs[tid] = sq;
        }
        __syncthreads();
        for (int k = 0; k < 128; ++k) {
            const float4* cp = (const float4*)&cbs[k * 64];
            float d0 = 0.f, d1 = 0.f;
#pragma unroll
            for (int m = 0; m < 16; ++m) {
                float4 c = cp[m];
                d0 += zv[0][4 * m] * c.x + zv[0][4 * m + 1] * c.y
                    + zv[0][4 * m + 2] * c.z + zv[0][4 * m + 3] * c.w;
                d1 += zv[1][4 * m] * c.x + zv[1][4 * m + 1] * c.y
                    + zv[1][4 * m + 2] * c.z + zv[1][4 * m + 3] * c.w;
            }
            float dist0 = sqs[k] - 2.f * d0;
            float dist1 = sqs[k] - 2.f * d1;
            if (dist0 < best0) { best0 = dist0; bi0 = ch * 128 + k; }
            if (dist1 < best1) { best1 = dist1; bi1 = ch * 128 + k; }
        }
    }

    float err = 0.f;
#pragma unroll
    for (int rr = 0; rr < 2; ++rr) {
        int r = rr ? rB : rA;
        int bi = rr ? bi1 : bi0;
        int n = r >> 12, s = r & 4095;
        const float* crow = cb + (size_t)bi * 64;
        short* qrow = qb + (size_t)r * 64;
#pragma unroll
        for (int d = 0; d < 64; ++d) {
            float c = crow[d];
            float dd = zv[rr][d] - c;
            err += dd * dd;
            quant[((size_t)((n << 6) + d)) * 4096 + s] = c;
            qrow[d] = f2b(c);
        }
        idxp[r] = bi;
        atomicAdd(&counts[bi], 1);
    }
#pragma unroll
    for (int o = 32; o; o >>= 1) err += __shfl_down(err, o, 64);
    if ((tid & 63) == 0) atomicAdd(loss_sum, err);
}

__global__ __launch_bounds__(512)
void fin_k(const int* __restrict__ counts, const float* __restrict__ loss_sum,
           float* out_loss, float* out_perp)
{
    __shared__ float red[512];
    const int t = threadIdx.x;
    float avg = (float)counts[t] * (1.0f / 65536.0f);
    red[t] = avg * logf(avg + 1e-10f);
    __syncthreads();
    for (int st = 256; st > 0; st >>= 1) {
        if (t < st) red[t] += red[t + st];
        __syncthreads();
    }
    if (t == 0) {
        *out_perp = expf(-red[0]);
        *out_loss = loss_sum[0] * (1.25f / 4194304.0f);
    }
}

__global__ __launch_bounds__(256)
void enc_k(const int* __restrict__ idxp, float4* __restrict__ enc)
{
    int i = blockIdx.x * 256 + threadIdx.x;    // < 8388608 float4s
    int r = i >> 7, c4 = (i & 127) * 4;
    int k = idxp[r];
    float4 v;
    v.x = (k == c4)     ? 1.f : 0.f;
    v.y = (k == c4 + 1) ? 1.f : 0.f;
    v.z = (k == c4 + 2) ? 1.f : 0.f;
    v.w = (k == c4 + 3) ? 1.f : 0.f;
    enc[i] = v;
}

// ---------------------------------------------------------------------------
extern "C" void kernel_launch(void* const* d_in, const int* in_sizes, int n_in,
                              void* d_out, int out_size, void* d_ws, size_t ws_size,
                              hipStream_t stream)
{
    const float* x    = (const float*)d_in[0];
    const float* ew1  = (const float*)d_in[1];
    const float* eb1  = (const float*)d_in[2];
    const float* ew2  = (const float*)d_in[3];
    const float* eb2  = (const float*)d_in[4];
    const float* ew3  = (const float*)d_in[5];
    const float* eb3  = (const float*)d_in[6];
    const float* er1a = (const float*)d_in[7];
    const float* er1b = (const float*)d_in[8];
    const float* er2a = (const float*)d_in[9];
    const float* er2b = (const float*)d_in[10];
    const float* pw   = (const float*)d_in[11];
    const float* pb   = (const float*)d_in[12];
    const float* cb   = (const float*)d_in[13];
    const float* dw1w = (const float*)d_in[14];
    const float* db1  = (const float*)d_in[15];
    const float* dr1a = (const float*)d_in[16];
    const float* dr1b = (const float*)d_in[17];
    const float* dr2a = (const float*)d_in[18];
    const float* dr2b = (const float*)d_in[19];
    const float* dtw1 = (const float*)d_in[20];
    const float* dtb1 = (const float*)d_in[21];
    const float* dtw2 = (const float*)d_in[22];
    const float* dtb2 = (const float*)d_in[23];

    char* wsb = (char*)d_ws;
    short* wbase = (short*)wsb;
    short* wt2   = wbase;
    short* wt3   = wbase + 131072;
    short* wr1a  = wbase + 278528;
    short* wr1b  = wbase + 315392;
    short* wr2a  = wbase + 319488;
    short* wr2b  = wbase + 356352;
    short* wpwt  = wbase + 360448;
    short* wd1   = wbase + 368640;
    short* wdr1a = wbase + 442368;
    short* wdr1b = wbase + 479232;
    short* wdr2a = wbase + 483328;
    short* wdr2b = wbase + 520192;
    short* wtt1  = wbase + 524288;

    short* h2   = (short*)(wsb + 1310720);
    short* buf  = (short*)(wsb + 18087936);
    short* mid  = (short*)(wsb + 34865152);
    short* qb   = (short*)(wsb + 39059456);
    float* z    = (float*)(wsb + 47448064);
    int*   idx  = (int*)  (wsb + 64225280);
    int*   counts   = (int*)(wsb + 64487424);
    float* loss_sum = (float*)(wsb + 64489472);
    if (ws_size < (size_t)64489480) return;

    float* out    = (float*)d_out;
    float* o_loss = out;
    float* xrec   = out + 1;
    float* o_perp = out + 1048577;
    float* enc    = out + 1048578;
    float* quant  = out + 34603010;
    short* h1  = (short*)((char*)d_out + (size_t)1048580 * 4);
    short* dt1 = h1 + 16777216;

    hipMemsetAsync(counts, 0, 516 * 4, stream);

    WtArgs wa;
    wa.d[0]  = { ew2,  128,  64, 16, 0, 0      };
    wa.d[1]  = { ew3,  128, 128,  9, 0, 131072 };
    wa.d[2]  = { er1a,  32, 128,  9, 0, 278528 };
    wa.d[3]  = { er1b, 128,  32,  1, 0, 315392 };
    wa.d[4]  = { er2a,  32, 128,  9, 0, 319488 };
    wa.d[5]  = { er2b, 128,  32,  1, 0, 356352 };
    wa.d[6]  = { pw,    64, 128,  1, 0, 360448 };
    wa.d[7]  = { dw1w, 128,  64,  9, 0, 368640 };
    wa.d[8]  = { dr1a,  32, 128,  9, 0, 442368 };
    wa.d[9]  = { dr1b, 128,  32,  1, 0, 479232 };
    wa.d[10] = { dr2a,  32, 128,  9, 0, 483328 };
    wa.d[11] = { dr2b, 128,  32,  1, 0, 520192 };
    wa.d[12] = { dtw1,  64, 128, 16, 1, 524288 };
    wa.total = 655360;
    wtall_k<<<dim3(2560), TPB, 0, stream>>>(wa, wbase);

    // ---- encoder ----
    conv1_k<<<dim3(128, 16), TPB, 0, stream>>>(x, ew1, eb1, h1);
    mconv_k<4,4,2,1, 64,128,false,true ,false,false><<<dim3(32,16), TPB, 0, stream>>>(h1,  wt2,  eb2, nullptr, h2);
    mconv_k<3,3,1,1,128,128,false,false,false,false><<<dim3(32,16), TPB, 0, stream>>>(h2,  wt3,  eb3, nullptr, buf);
    mconv_k<3,3,1,1,128, 32,true ,true ,false,false><<<dim3(32,16), TPB, 0, stream>>>(buf, wr1a, nullptr, nullptr, mid);
    mconv_k<1,1,1,0, 32,128,false,false,true ,false><<<dim3(32,16), TPB, 0, stream>>>(mid, wr1b, nullptr, buf, buf);
    mconv_k<3,3,1,1,128, 32,true ,true ,false,false><<<dim3(32,16), TPB, 0, stream>>>(buf, wr2a, nullptr, nullptr, mid);
    mconv_k<1,1,1,0, 32,128,false,false,true ,false><<<dim3(32,16), TPB, 0, stream>>>(mid, wr2b, nullptr, buf, buf);
    mconv_k<1,1,1,0,128, 64,true ,false,false,true ><<<dim3(32,16), TPB, 0, stream>>>(buf, wpwt, pb, nullptr, z);

    // ---- VQ ----
    vq_k<<<dim3(128), TPB, 0, stream>>>(z, cb, quant, qb, idx, counts, loss_sum);
    fin_k<<<dim3(1), 512, 0, stream>>>(counts, loss_sum, o_loss, o_perp);

    // ---- decoder ----
    mconv_k<3,3,1,1, 64,128,false,false,false,false><<<dim3(32,16), TPB, 0, stream>>>(qb,  wd1,   db1, nullptr, buf);
    mconv_k<3,3,1,1,128, 32,true ,true ,false,false><<<dim3(32,16), TPB, 0, stream>>>(buf, wdr1a, nullptr, nullptr, mid);
    mconv_k<1,1,1,0, 32,128,false,false,true ,false><<<dim3(32,16), TPB, 0, stream>>>(mid, wdr1b, nullptr, buf, buf);
    mconv_k<3,3,1,1,128, 32,true ,true ,false,false><<<dim3(32,16), TPB, 0, stream>>>(buf, wdr2a, nullptr, nullptr, mid);
    mconv_k<1,1,1,0, 32,128,false,false,true ,false><<<dim3(32,16), TPB, 0, stream>>>(mid, wdr2b, nullptr, buf, buf);
    mct1_k<<<dim3(128, 16), TPB, 0, stream>>>(buf, wtt1, dtb1, dt1);
    convt2_k<<<dim3(4096), TPB, 0, stream>>>(dt1, dtw2, dtb2, xrec);

    // ---- encodings (last) ----
    enc_k<<<dim3(32768), TPB, 0, stream>>>(idx, (float4*)enc);
}

// Round 4
// 882.152 us; speedup vs baseline: 5.2894x; 1.1901x over previous
//
#include <hip/hip_runtime.h>

#define TPB 256

typedef __attribute__((ext_vector_type(8))) short s8v;
typedef __attribute__((ext_vector_type(4))) float f4v;
typedef __bf16 bf16x8v __attribute__((ext_vector_type(8)));

__device__ inline short f2b(float f) {
    unsigned u = __builtin_bit_cast(unsigned, f);
    unsigned r = (u + 0x7FFF + ((u >> 16) & 1)) >> 16;
    return (short)r;
}
__device__ inline float b2f(short s) {
    unsigned u = ((unsigned)(unsigned short)s) << 16;
    return __builtin_bit_cast(float, u);
}
__device__ inline f4v mfma16(s8v a, s8v b, f4v c) {
    return __builtin_amdgcn_mfma_f32_16x16x32_bf16(
        __builtin_bit_cast(bf16x8v, a), __builtin_bit_cast(bf16x8v, b), c, 0, 0, 0);
}

// ---------------------------------------------------------------------------
// Fused weight transpose: OIHW (or IOHW) fp32 -> [tap][co][ci] bf16
// ---------------------------------------------------------------------------
struct WtDesc { const float* src; int CO, CI, T, iohw, start; };
struct WtArgs { WtDesc d[13]; int total; };

__global__ __launch_bounds__(256)
void wtall_k(WtArgs a, short* dst)
{
    int i = blockIdx.x * 256 + threadIdx.x;
    if (i >= a.total) return;
    int s = 0;
    for (int j = 1; j < 13; ++j) if (i >= a.d[j].start) s = j;
    int off = i - a.d[s].start;
    int CI = a.d[s].CI, CO = a.d[s].CO, T = a.d[s].T;
    int ci = off % CI; int rest = off / CI; int co = rest % CO; int tap = rest / CO;
    float v = a.d[s].iohw ? a.d[s].src[(ci * CO + co) * T + tap]
                          : a.d[s].src[(co * CI + ci) * T + tap];
    dst[i] = f2b(v);
}

// Codebook split: cb fp32 [512][64] -> hi bf16, lo bf16, |c|^2 fp32
__global__ __launch_bounds__(256)
void cbprep_k(const float* __restrict__ cb, short* __restrict__ cbh,
              short* __restrict__ cbl, float* __restrict__ cbsq)
{
    int c = blockIdx.x * 256 + threadIdx.x;   // 0..511
    const float* src = cb + (size_t)c * 64;
    float sq = 0.f;
#pragma unroll
    for (int g = 0; g < 8; ++g) {
        s8v hi, lo;
#pragma unroll
        for (int j = 0; j < 8; ++j) {
            float v = src[g * 8 + j];
            sq += v * v;
            short h = f2b(v);
            hi[j] = h;
            lo[j] = f2b(v - b2f(h));
        }
        *(s8v*)(cbh + (size_t)c * 64 + g * 8) = hi;
        *(s8v*)(cbl + (size_t)c * 64 + g * 8) = lo;
    }
    cbsq[c] = sq;
}

// ---------------------------------------------------------------------------
// conv1: x (16,1,256,256) fp32 -> h1 NHWC bf16 (16,128,128,64), k4 s2 p1,
// bias+relu. One block per (n, oh); lane = co; no spill.
// ---------------------------------------------------------------------------
__global__ __launch_bounds__(256)
void conv1_k(const float* __restrict__ x, const float* __restrict__ w,
             const float* __restrict__ bias, short* __restrict__ out)
{
    __shared__ float sx[4 * 256];
    const int tid = threadIdx.x;
    const int oh = blockIdx.x, n = blockIdx.y;
    const int co = tid & 63, wv = tid >> 6;

    float wr[16];
#pragma unroll
    for (int t = 0; t < 16; ++t) wr[t] = w[co * 16 + t];
    const float b = bias[co];

    const float* xp = x + (size_t)n * 65536;
    for (int e = tid; e < 1024; e += 256) {
        int kh = e >> 8, col = e & 255;
        int ih = oh * 2 - 1 + kh;
        sx[e] = ((unsigned)ih < 256u) ? xp[ih * 256 + col] : 0.f;
    }
    __syncthreads();

    short* op = out + (((size_t)n * 128 + oh) * 128) * 64 + co;
#pragma unroll 4
    for (int i = 0; i < 32; ++i) {
        int ow = wv * 32 + i;
        int iwb = ow * 2 - 1;
        float acc = b;
#pragma unroll
        for (int kh = 0; kh < 4; ++kh) {
#pragma unroll
            for (int kw = 0; kw < 4; ++kw) {
                int iw = iwb + kw;
                float v = ((unsigned)iw < 256u) ? sx[kh * 256 + iw] : 0.f;
                acc = fmaf(v, wr[kh * 4 + kw], acc);
            }
        }
        op[(size_t)ow * 64] = f2b(fmaxf(acc, 0.f));
    }
}

// ---------------------------------------------------------------------------
// MFMA implicit-GEMM conv. in NHWC bf16 (64S x 64S x CI), out NHWC 64x64xCO.
// ---------------------------------------------------------------------------
template<int KH, int KW, int S, int P, int CI, int CO,
         bool RELU_IN, bool RELU_OUT, bool RES, bool OUT_F32>
__global__ __launch_bounds__(256)
void mconv_k(const short* __restrict__ in, const short* __restrict__ wt,
             const float* __restrict__ bias, const short* __restrict__ res,
             void* __restrict__ outv)
{
    constexpr int NT = CO / 16;
    constexpr int KC = CI / 32;
    constexpr int T  = KH * KW;
    constexpr int H  = 64 * S, W = 64 * S;
    __shared__ short sA[128 * 40];
    __shared__ short sB[CO * 40];

    const int tid = threadIdx.x;
    const int oh0 = blockIdx.x * 2;
    const int n   = blockIdx.y;
    const short* inb = in + (size_t)n * H * W * CI;
    const int w = tid >> 6, l = tid & 63, rl = l & 15, qd = l >> 4;

    f4v acc0[NT], acc1[NT];
#pragma unroll
    for (int nt = 0; nt < NT; ++nt) { acc0[nt] = (f4v)0.f; acc1[nt] = (f4v)0.f; }

    for (int tap = 0; tap < T; ++tap) {
        const int kh = tap / KW, kw = tap % KW;
        const short* wp = wt + (size_t)tap * CO * CI;
        for (int kc = 0; kc < KC; ++kc) {
            __syncthreads();
#pragma unroll
            for (int e = tid; e < 512; e += 256) {
                int row = e >> 2, kcn = e & 3;
                int ohl = row >> 6, ow = row & 63;
                int ih = (oh0 + ohl) * S - P + kh;
                int iw = ow * S - P + kw;
                s8v v = (s8v)0;
                if ((unsigned)ih < (unsigned)H && (unsigned)iw < (unsigned)W) {
                    v = *(const s8v*)(inb + ((size_t)ih * W + iw) * CI + kc * 32 + kcn * 8);
                    if (RELU_IN) {
#pragma unroll
                        for (int j = 0; j < 8; ++j) if (v[j] < (short)0) v[j] = 0;
                    }
                }
                *(s8v*)&sA[row * 40 + kcn * 8] = v;
            }
            for (int e = tid; e < CO * 4; e += 256) {
                int co = e >> 2, kcn = e & 3;
                *(s8v*)&sB[co * 40 + kcn * 8] =
                    *(const s8v*)(wp + (size_t)co * CI + kc * 32 + kcn * 8);
            }
            __syncthreads();
            s8v a0 = *(const s8v*)&sA[(w * 32 + rl) * 40 + qd * 8];
            s8v a1 = *(const s8v*)&sA[(w * 32 + 16 + rl) * 40 + qd * 8];
#pragma unroll
            for (int nt = 0; nt < NT; ++nt) {
                s8v b = *(const s8v*)&sB[(nt * 16 + rl) * 40 + qd * 8];
                acc0[nt] = mfma16(a0, b, acc0[nt]);
                acc1[nt] = mfma16(a1, b, acc1[nt]);
            }
        }
    }

#pragma unroll
    for (int sub = 0; sub < 2; ++sub) {
#pragma unroll
        for (int rg = 0; rg < 4; ++rg) {
            int m = w * 32 + sub * 16 + qd * 4 + rg;
            int ohl = m >> 6, ow = m & 63;
            size_t pb = ((size_t)n * 4096 + (size_t)(oh0 + ohl) * 64 + ow) * CO;
#pragma unroll
            for (int nt = 0; nt < NT; ++nt) {
                int co = nt * 16 + rl;
                float v = sub ? acc1[nt][rg] : acc0[nt][rg];
                if (bias) v += bias[co];
                if (RES) v += b2f(res[pb + co]);
                if (RELU_OUT) v = fmaxf(v, 0.f);
                if (OUT_F32) ((float*)outv)[pb + co] = v;
                else         ((short*)outv)[pb + co] = f2b(v);
            }
        }
    }
}

// ---------------------------------------------------------------------------
// ConvT1 as parity conv (MFMA): in NHWC bf16 (64,64,128) -> out (128,128,64)
// ---------------------------------------------------------------------------
__global__ __launch_bounds__(256)
void mct1_k(const short* __restrict__ in, const short* __restrict__ wt,
            const float* __restrict__ bias, short* __restrict__ out)
{
    __shared__ short sA[128 * 40];
    __shared__ short sB[64 * 40];
    const int tid = threadIdx.x;
    const int bx = blockIdx.x;
    const int n  = blockIdx.y;
    const int P  = bx & 1;
    const int q2 = bx >> 1;
    const int oh0 = (q2 >> 1) * 4 + (q2 & 1);
    const int p  = (oh0 + 1) & 1;
    const int ihb0 = (oh0 + 1 - p) >> 1;
    const short* inb = in + (size_t)n * 4096 * 128;
    const int w = tid >> 6, l = tid & 63, rl = l & 15, qd = l >> 4;

    f4v acc0[4], acc1[4];
#pragma unroll
    for (int nt = 0; nt < 4; ++nt) { acc0[nt] = (f4v)0.f; acc1[nt] = (f4v)0.f; }

    for (int a = 0; a < 2; ++a)
    for (int b = 0; b < 2; ++b) {
        const int kh = p + 2 * a;
        const int kw = (1 - P) + 2 * b;
        const short* wp = wt + (size_t)(kh * 4 + kw) * 64 * 128;
        for (int kc = 0; kc < 4; ++kc) {
            __syncthreads();
#pragma unroll
            for (int e = tid; e < 512; e += 256) {
                int row = e >> 2, kcn = e & 3;
                int ohl = row >> 6, j = row & 63;
                int ih = ihb0 + ohl - a;
                int iw = j + P - b;
                s8v v = (s8v)0;
                if ((unsigned)ih < 64u && (unsigned)iw < 64u)
                    v = *(const s8v*)(inb + ((size_t)(ih * 64 + iw)) * 128 + kc * 32 + kcn * 8);
                *(s8v*)&sA[row * 40 + kcn * 8] = v;
            }
            {
                int e = tid;
                if (e < 256) {
                    int co = e >> 2, kcn = e & 3;
                    *(s8v*)&sB[co * 40 + kcn * 8] =
                        *(const s8v*)(wp + (size_t)co * 128 + kc * 32 + kcn * 8);
                }
            }
            __syncthreads();
            s8v a0 = *(const s8v*)&sA[(w * 32 + rl) * 40 + qd * 8];
            s8v a1 = *(const s8v*)&sA[(w * 32 + 16 + rl) * 40 + qd * 8];
#pragma unroll
            for (int nt = 0; nt < 4; ++nt) {
                s8v bb = *(const s8v*)&sB[(nt * 16 + rl) * 40 + qd * 8];
                acc0[nt] = mfma16(a0, bb, acc0[nt]);
                acc1[nt] = mfma16(a1, bb, acc1[nt]);
            }
        }
    }

#pragma unroll
    for (int sub = 0; sub < 2; ++sub) {
#pragma unroll
        for (int rg = 0; rg < 4; ++rg) {
            int m = w * 32 + sub * 16 + qd * 4 + rg;
            int ohl = m >> 6, j = m & 63;
            int oh = oh0 + 2 * ohl, ow = 2 * j + P;
            size_t pb = (((size_t)n * 128 + oh) * 128 + ow) * 64;
#pragma unroll
            for (int nt = 0; nt < 4; ++nt) {
                int co = nt * 16 + rl;
                float v = (sub ? acc1[nt][rg] : acc0[nt][rg]) + bias[co];
                out[pb + co] = f2b(fmaxf(v, 0.f));
            }
        }
    }
}

// ---------------------------------------------------------------------------
// ConvT2: in NHWC bf16 (16,128,128,64) -> x_rec fp32 (16,256,256), k4 s2 p1.
// ---------------------------------------------------------------------------
__global__ __launch_bounds__(256)
void convt2_k(const short* __restrict__ in, const float* __restrict__ w,
              const float* __restrict__ bias, float* __restrict__ out)
{
    __shared__ float sw[16 * 64];
    const int tid = threadIdx.x;
    for (int e = tid; e < 1024; e += 256) { int ci = e >> 4, tap = e & 15; sw[tap * 64 + ci] = w[e]; }
    __syncthreads();

    const int i = blockIdx.x * 256 + tid;
    const int n = i >> 16, s = i & 65535;
    const int oh = s >> 8, ow = s & 255;

    const int p = (oh + 1) & 1, q = (ow + 1) & 1;
    const int ihb = (oh + 1 - p) >> 1, iwb = (ow + 1 - q) >> 1;

    float acc = bias[0];
#pragma unroll
    for (int a = 0; a < 2; ++a) {
        int ih = ihb - a, kh = p + 2 * a;
        bool vr = (unsigned)ih < 128u;
#pragma unroll
        for (int b = 0; b < 2; ++b) {
            int iw = iwb - b, kw = q + 2 * b;
            if (vr && (unsigned)iw < 128u) {
                const short* ip = in + (((size_t)n * 128 + ih) * 128 + iw) * 64;
                const float* wp = &sw[(kh * 4 + kw) * 64];
#pragma unroll
                for (int c = 0; c < 64; c += 8) {
                    s8v v = *(const s8v*)(ip + c);
#pragma unroll
                    for (int j = 0; j < 8; ++j) acc += b2f(v[j]) * wp[c + j];
                }
            }
        }
    }
    out[i] = acc;
}

// ---------------------------------------------------------------------------
// VQ via MFMA distance GEMM, split-bf16 (zh*ch + zh*cl + zl*ch ~ fp32 dot).
// 512 blocks x 4 waves; 128 rows/block; codes chunked 4x128, B direct from
// global (L2-hot 128 KB codebook); argmin in-register + 16-lane shfl reduce.
// ---------------------------------------------------------------------------
__global__ __launch_bounds__(256)
void vqm_k(const float* __restrict__ z, const short* __restrict__ cbh,
           const short* __restrict__ cbl, const float* __restrict__ cbsq,
           const float* __restrict__ cb,
           float* __restrict__ quant, short* __restrict__ qb,
           int* __restrict__ idxp, int* __restrict__ counts,
           float* __restrict__ loss_sum)
{
    __shared__ int sidx[128];
    const int tid = threadIdx.x;
    const int w = tid >> 6, l = tid & 63, rl = l & 15, qd = l >> 4;
    const int r0 = blockIdx.x * 128;

    // load A fragments (z rows) and split hi/lo
    s8v zh[2][2], zl[2][2];
#pragma unroll
    for (int sub = 0; sub < 2; ++sub) {
        int row = r0 + w * 32 + sub * 16 + rl;
#pragma unroll
        for (int kc = 0; kc < 2; ++kc) {
            const float* zp = z + (size_t)row * 64 + kc * 32 + qd * 8;
            s8v hi, lo;
#pragma unroll
            for (int j = 0; j < 8; ++j) {
                float v = zp[j];
                short h = f2b(v);
                hi[j] = h;
                lo[j] = f2b(v - b2f(h));
            }
            zh[sub][kc] = hi; zl[sub][kc] = lo;
        }
    }

    float best[2][4];
    int   bidx[2][4];
#pragma unroll
    for (int sub = 0; sub < 2; ++sub)
#pragma unroll
        for (int rg = 0; rg < 4; ++rg) { best[sub][rg] = 3.4e38f; bidx[sub][rg] = 0; }

    for (int ch = 0; ch < 4; ++ch) {
        f4v acc[2][8];
#pragma unroll
        for (int sub = 0; sub < 2; ++sub)
#pragma unroll
            for (int nt = 0; nt < 8; ++nt) acc[sub][nt] = (f4v)0.f;

        float sq[8];
#pragma unroll
        for (int nt = 0; nt < 8; ++nt) sq[nt] = cbsq[ch * 128 + nt * 16 + rl];

#pragma unroll
        for (int kc = 0; kc < 2; ++kc) {
#pragma unroll
            for (int nt = 0; nt < 8; ++nt) {
                int code = ch * 128 + nt * 16 + rl;
                s8v bh = *(const s8v*)(cbh + (size_t)code * 64 + kc * 32 + qd * 8);
                s8v bl = *(const s8v*)(cbl + (size_t)code * 64 + kc * 32 + qd * 8);
#pragma unroll
                for (int sub = 0; sub < 2; ++sub) {
                    acc[sub][nt] = mfma16(zh[sub][kc], bh, acc[sub][nt]);
                    acc[sub][nt] = mfma16(zh[sub][kc], bl, acc[sub][nt]);
                    acc[sub][nt] = mfma16(zl[sub][kc], bh, acc[sub][nt]);
                }
            }
        }

#pragma unroll
        for (int sub = 0; sub < 2; ++sub)
#pragma unroll
            for (int rg = 0; rg < 4; ++rg) {
                float bd = best[sub][rg]; int bi = bidx[sub][rg];
#pragma unroll
                for (int nt = 0; nt < 8; ++nt) {
                    float d = sq[nt] - 2.f * acc[sub][nt][rg];
                    int code = ch * 128 + nt * 16 + rl;
                    if (d < bd) { bd = d; bi = code; }
                }
                best[sub][rg] = bd; bidx[sub][rg] = bi;
            }
    }

    // cross-lane argmin over rl (16 lanes per qd group), first-min tie-break
#pragma unroll
    for (int sub = 0; sub < 2; ++sub)
#pragma unroll
        for (int rg = 0; rg < 4; ++rg) {
            float bd = best[sub][rg]; int bi = bidx[sub][rg];
#pragma unroll
            for (int off = 1; off < 16; off <<= 1) {
                float od = __shfl_xor(bd, off, 64);
                int   oi = __shfl_xor(bi, off, 64);
                if (od < bd || (od == bd && oi < bi)) { bd = od; bi = oi; }
            }
            if (rl == 0) sidx[w * 32 + sub * 16 + qd * 4 + rg] = bi;
        }
    __syncthreads();

    // epilogue: exact fp32 error, quant (NCHW), qb (bf16 NHWC), idx, counts
    const int rr = tid & 127, half = tid >> 7;
    const int r = r0 + rr;
    const int bi = sidx[rr];
    const int n = r >> 12, s = r & 4095;
    const float* zr = z  + (size_t)r * 64 + half * 32;
    const float* cr = cb + (size_t)bi * 64 + half * 32;
    short* qrow = qb + (size_t)r * 64 + half * 32;
    float err = 0.f;
#pragma unroll
    for (int g = 0; g < 4; ++g) {
        s8v qv;
#pragma unroll
        for (int j = 0; j < 8; ++j) {
            int d = g * 8 + j;
            float c = cr[d];
            float dd = zr[d] - c;
            err += dd * dd;
            qv[j] = f2b(c);
            quant[((size_t)((n << 6) + half * 32 + d)) * 4096 + s] = c;
        }
        *(s8v*)(qrow + g * 8) = qv;
    }
    if (tid < 128) {
        idxp[r0 + tid] = sidx[tid];
        atomicAdd(&counts[sidx[tid]], 1);
    }
#pragma unroll
    for (int o = 32; o; o >>= 1) err += __shfl_down(err, o, 64);
    if (l == 0) atomicAdd(loss_sum, err);
}

__global__ __launch_bounds__(512)
void fin_k(const int* __restrict__ counts, const float* __restrict__ loss_sum,
           float* out_loss, float* out_perp)
{
    __shared__ float red[512];
    const int t = threadIdx.x;
    float avg = (float)counts[t] * (1.0f / 65536.0f);
    red[t] = avg * logf(avg + 1e-10f);
    __syncthreads();
    for (int st = 256; st > 0; st >>= 1) {
        if (t < st) red[t] += red[t + st];
        __syncthreads();
    }
    if (t == 0) {
        *out_perp = expf(-red[0]);
        *out_loss = loss_sum[0] * (1.25f / 4194304.0f);
    }
}

__global__ __launch_bounds__(256)
void enc_k(const int* __restrict__ idxp, float4* __restrict__ enc)
{
    int i = blockIdx.x * 256 + threadIdx.x;
    int r = i >> 7, c4 = (i & 127) * 4;
    int k = idxp[r];
    float4 v;
    v.x = (k == c4)     ? 1.f : 0.f;
    v.y = (k == c4 + 1) ? 1.f : 0.f;
    v.z = (k == c4 + 2) ? 1.f : 0.f;
    v.w = (k == c4 + 3) ? 1.f : 0.f;
    enc[i] = v;
}

// ---------------------------------------------------------------------------
extern "C" void kernel_launch(void* const* d_in, const int* in_sizes, int n_in,
                              void* d_out, int out_size, void* d_ws, size_t ws_size,
                              hipStream_t stream)
{
    const float* x    = (const float*)d_in[0];
    const float* ew1  = (const float*)d_in[1];
    const float* eb1  = (const float*)d_in[2];
    const float* ew2  = (const float*)d_in[3];
    const float* eb2  = (const float*)d_in[4];
    const float* ew3  = (const float*)d_in[5];
    const float* eb3  = (const float*)d_in[6];
    const float* er1a = (const float*)d_in[7];
    const float* er1b = (const float*)d_in[8];
    const float* er2a = (const float*)d_in[9];
    const float* er2b = (const float*)d_in[10];
    const float* pw   = (const float*)d_in[11];
    const float* pb   = (const float*)d_in[12];
    const float* cb   = (const float*)d_in[13];
    const float* dw1w = (const float*)d_in[14];
    const float* db1  = (const float*)d_in[15];
    const float* dr1a = (const float*)d_in[16];
    const float* dr1b = (const float*)d_in[17];
    const float* dr2a = (const float*)d_in[18];
    const float* dr2b = (const float*)d_in[19];
    const float* dtw1 = (const float*)d_in[20];
    const float* dtb1 = (const float*)d_in[21];
    const float* dtw2 = (const float*)d_in[22];
    const float* dtb2 = (const float*)d_in[23];

    char* wsb = (char*)d_ws;
    short* wbase = (short*)wsb;
    short* wt2   = wbase;
    short* wt3   = wbase + 131072;
    short* wr1a  = wbase + 278528;
    short* wr1b  = wbase + 315392;
    short* wr2a  = wbase + 319488;
    short* wr2b  = wbase + 356352;
    short* wpwt  = wbase + 360448;
    short* wd1   = wbase + 368640;
    short* wdr1a = wbase + 442368;
    short* wdr1b = wbase + 479232;
    short* wdr2a = wbase + 483328;
    short* wdr2b = wbase + 520192;
    short* wtt1  = wbase + 524288;

    short* h2   = (short*)(wsb + 1310720);
    short* buf  = (short*)(wsb + 18087936);
    short* mid  = (short*)(wsb + 34865152);
    short* qb   = (short*)(wsb + 39059456);
    float* z    = (float*)(wsb + 47448064);
    int*   idx  = (int*)  (wsb + 64225280);
    int*   counts   = (int*)(wsb + 64487424);
    float* loss_sum = (float*)(wsb + 64489472);
    if (ws_size < (size_t)64489480) return;

    float* out    = (float*)d_out;
    float* o_loss = out;
    float* xrec   = out + 1;
    float* o_perp = out + 1048577;
    float* enc    = out + 1048578;
    float* quant  = out + 34603010;
    // scratch inside enc output region (dead until enc_k, which runs last):
    short* h1  = (short*)((char*)d_out + (size_t)1048580 * 4);      // 32 MB
    short* dt1 = h1 + 16777216;                                     // 32 MB
    // codebook split arrays parked high in the enc region (no overlap):
    char*  encB = (char*)d_out + (size_t)1048580 * 4;
    short* cbh  = (short*)(encB + ((size_t)120 << 20));
    short* cbl  = cbh + 32768;
    float* cbsq = (float*)(cbl + 32768);

    hipMemsetAsync(counts, 0, 516 * 4, stream);

    WtArgs wa;
    wa.d[0]  = { ew2,  128,  64, 16, 0, 0      };
    wa.d[1]  = { ew3,  128, 128,  9, 0, 131072 };
    wa.d[2]  = { er1a,  32, 128,  9, 0, 278528 };
    wa.d[3]  = { er1b, 128,  32,  1, 0, 315392 };
    wa.d[4]  = { er2a,  32, 128,  9, 0, 319488 };
    wa.d[5]  = { er2b, 128,  32,  1, 0, 356352 };
    wa.d[6]  = { pw,    64, 128,  1, 0, 360448 };
    wa.d[7]  = { dw1w, 128,  64,  9, 0, 368640 };
    wa.d[8]  = { dr1a,  32, 128,  9, 0, 442368 };
    wa.d[9]  = { dr1b, 128,  32,  1, 0, 479232 };
    wa.d[10] = { dr2a,  32, 128,  9, 0, 483328 };
    wa.d[11] = { dr2b, 128,  32,  1, 0, 520192 };
    wa.d[12] = { dtw1,  64, 128, 16, 1, 524288 };
    wa.total = 655360;
    wtall_k<<<dim3(2560), TPB, 0, stream>>>(wa, wbase);
    cbprep_k<<<dim3(2), TPB, 0, stream>>>(cb, cbh, cbl, cbsq);

    // ---- encoder ----
    conv1_k<<<dim3(128, 16), TPB, 0, stream>>>(x, ew1, eb1, h1);
    mconv_k<4,4,2,1, 64,128,false,true ,false,false><<<dim3(32,16), TPB, 0, stream>>>(h1,  wt2,  eb2, nullptr, h2);
    mconv_k<3,3,1,1,128,128,false,false,false,false><<<dim3(32,16), TPB, 0, stream>>>(h2,  wt3,  eb3, nullptr, buf);
    mconv_k<3,3,1,1,128, 32,true ,true ,false,false><<<dim3(32,16), TPB, 0, stream>>>(buf, wr1a, nullptr, nullptr, mid);
    mconv_k<1,1,1,0, 32,128,false,false,true ,false><<<dim3(32,16), TPB, 0, stream>>>(mid, wr1b, nullptr, buf, buf);
    mconv_k<3,3,1,1,128, 32,true ,true ,false,false><<<dim3(32,16), TPB, 0, stream>>>(buf, wr2a, nullptr, nullptr, mid);
    mconv_k<1,1,1,0, 32,128,false,false,true ,false><<<dim3(32,16), TPB, 0, stream>>>(mid, wr2b, nullptr, buf, buf);
    mconv_k<1,1,1,0,128, 64,true ,false,false,true ><<<dim3(32,16), TPB, 0, stream>>>(buf, wpwt, pb, nullptr, z);

    // ---- VQ ----
    vqm_k<<<dim3(512), TPB, 0, stream>>>(z, cbh, cbl, cbsq, cb, quant, qb, idx, counts, loss_sum);
    fin_k<<<dim3(1), 512, 0, stream>>>(counts, loss_sum, o_loss, o_perp);

    // ---- decoder ----
    mconv_k<3,3,1,1, 64,128,false,false,false,false><<<dim3(32,16), TPB, 0, stream>>>(qb,  wd1,   db1, nullptr, buf);
    mconv_k<3,3,1,1,128, 32,true ,true ,false,false><<<dim3(32,16), TPB, 0, stream>>>(buf, wdr1a, nullptr, nullptr, mid);
    mconv_k<1,1,1,0, 32,128,false,false,true ,false><<<dim3(32,16), TPB, 0, stream>>>(mid, wdr1b, nullptr, buf, buf);
    mconv_k<3,3,1,1,128, 32,true ,true ,false,false><<<dim3(32,16), TPB, 0, stream>>>(buf, wdr2a, nullptr, nullptr, mid);
    mconv_k<1,1,1,0, 32,128,false,false,true ,false><<<dim3(32,16), TPB, 0, stream>>>(mid, wdr2b, nullptr, buf, buf);
    mct1_k<<<dim3(128, 16), TPB, 0, stream>>>(buf, wtt1, dtb1, dt1);
    convt2_k<<<dim3(4096), TPB, 0, stream>>>(dt1, dtw2, dtb2, xrec);

    // ---- encodings (last) ----
    enc_k<<<dim3(32768), TPB, 0, stream>>>(idx, (float4*)enc);
}